// Round 18
// baseline (286.546 us; speedup 1.0000x reference)
//
#include <hip/hip_runtime.h>
#include <hip/hip_bf16.h>

using short8 = __attribute__((ext_vector_type(8))) short;
using f32x4  = __attribute__((ext_vector_type(4))) float;
using u32x4  = __attribute__((ext_vector_type(4))) unsigned int;

#define DDIM 512
#define NROWS 1024
#define CCLS 100000
#define NCT 782            // c-tiles of 128
#define CPAD (NCT * 128)   // 100096 padded classes
#define GRID_BLOCKS 1280   // 5/CU resident (32KB LDS), persistent XCD-windowed

#define XSCALE 92.33248261689366f      // 64 * log2(e): acc = XSCALE * cos
#define INV_XSCALE 0.010830424696358f  // ln2/64: cos = acc * INV_XSCALE

__device__ inline unsigned int f2bf(float f) {
    unsigned int u = __float_as_uint(f);
    u += 0x7FFFu + ((u >> 16) & 1u);
    return u >> 16;
}

__device__ inline unsigned int pk2(float x, float y) {
    unsigned int r;
    asm("v_cvt_pk_bf16_f32 %0, %1, %2" : "=v"(r) : "v"(x), "v"(y));
    return r;
}

__device__ inline void gload_lds16(const void* g, void* l) {
    __builtin_amdgcn_global_load_lds(
        (const __attribute__((address_space(1))) void*)g,
        (__attribute__((address_space(3))) void*)l, 16, 0, 0);
}

// ------- kernel 1: normalize x rows -> bf16, scaled by 64*log2(e) ----------
__global__ __launch_bounds__(256) void norm_x(const float* __restrict__ x,
                                              unsigned short* __restrict__ xn) {
    const int row = blockIdx.x;
    const int tid = threadIdx.x;
    float2 v = *(const float2*)(x + (size_t)row * DDIM + tid * 2);
    float ss = v.x * v.x + v.y * v.y;
#pragma unroll
    for (int m = 1; m < 64; m <<= 1) ss += __shfl_xor(ss, m);
    __shared__ float wsum[4];
    if ((tid & 63) == 0) wsum[tid >> 6] = ss;
    __syncthreads();
    float inv = XSCALE / sqrtf(wsum[0] + wsum[1] + wsum[2] + wsum[3]);
    unsigned int packed = f2bf(v.x * inv) | (f2bf(v.y * inv) << 16);
    ((unsigned int*)xn)[(size_t)row * (DDIM / 2) + tid] = packed;
}

// ------- kernel 2: W -> PRE-NORMALIZED bf16 (one wave per row) --------------
__global__ __launch_bounds__(256) void norm_w_cvt(const float* __restrict__ W,
                                                  unsigned short* __restrict__ Wbf) {
    const int row  = blockIdx.x * 4 + (threadIdx.x >> 6);
    const int lane = threadIdx.x & 63;
    if (row < CCLS) {
        const float4* p = (const float4*)(W + (size_t)row * DDIM + lane * 8);
        float4 a = p[0], b = p[1];
        float ss = a.x*a.x + a.y*a.y + a.z*a.z + a.w*a.w
                 + b.x*b.x + b.y*b.y + b.z*b.z + b.w*b.w;
#pragma unroll
        for (int m = 1; m < 64; m <<= 1) ss += __shfl_xor(ss, m);
        float inv = (ss > 0.0f) ? (1.0f / sqrtf(ss)) : 0.0f;
        u32x4 u = { pk2(a.x * inv, a.y * inv), pk2(a.z * inv, a.w * inv),
                    pk2(b.x * inv, b.y * inv), pk2(b.z * inv, b.w * inv) };
        *(u32x4*)(Wbf + (size_t)row * DDIM + lane * 8) = u;
    } else {
        *(u32x4*)(Wbf + (size_t)row * DDIM + lane * 8) = u32x4{0u, 0u, 0u, 0u};
    }
}

// ---------------- kernel 3: GEMM + exp-rowsum + target ----------------------
// R10's proven loop (128x128 tile, BK=64, 4 waves 2x2, acc[4][4], single
// 32KB buffer, 2 barriers/k-step, pure-DMA staging) with:
//  - LDS trimmed to EXACTLY 32KB (lrow/llab deleted) -> 5 blocks/CU
//  - epilogue LDS-free: direct global atomics (64/block, fewer than before)
//    and direct L1-hot label loads; no barriers outside the k-loop
//  - acc = 92.33*cos directly (prenorm Wbf, scaled xn): epilogue is one
//    exp2f per element, no winv array
__global__ __launch_bounds__(256, 4) void arc_gemm(
    const unsigned short* __restrict__ xn,   // [1024][512] bf16 (x 92.33/||x||)
    const unsigned short* __restrict__ Wbf,  // [CPAD][512] bf16 (W/||W||, 0-pad)
    const int* __restrict__ labels,          // [1024]
    float* __restrict__ rowsum,              // [1024] (pre-zeroed)
    float* __restrict__ tcos)                // [1024]
{
    __shared__ __align__(16) unsigned short lsA[128 * 64]; // 16 KB
    __shared__ __align__(16) unsigned short lsW[128 * 64]; // 16 KB  (= 32 KB total)

    const int tid  = threadIdx.x;
    const int lane = tid & 63;
    const int wid  = tid >> 6;
    const int wr   = wid >> 1, wc = wid & 1;
    const int q    = lane >> 4;
    const int fr   = lane & 15;

    // DMA geometry: dest linear, source column pre-swizzled by row&7
    // (rule #21) -> conflict-free 16-row ds_read_b128 fragments.
    const int grow = tid >> 3;
    const int gcol = ((tid & 7) ^ (grow & 7)) * 8;   // bf16 units

    const int x    = blockIdx.x & 7;
    const int sidx = blockIdx.x >> 3;
    const int nct  = (NCT - 1 - x) / 8 + 1;
    const int npairs = nct * 8;

    for (int p = sidx; p < npairs; p += GRID_BLOCKS / 8) {
        const int c0 = (x + 8 * (p >> 3)) * 128;
        const int m0 = (p & 7) * 128;

        f32x4 acc[4][4];
#pragma unroll
        for (int i = 0; i < 4; ++i)
#pragma unroll
            for (int j = 0; j < 4; ++j) acc[i][j] = (f32x4)(0.0f);

#pragma unroll 1
        for (int k = 0; k < 8; ++k) {
            const int k0 = k * 64;
            __syncthreads();   // prev compute (or prev pair) done reading LDS
#pragma unroll
            for (int it = 0; it < 4; ++it)
                gload_lds16(xn + (size_t)(m0 + it * 32 + grow) * DDIM + k0 + gcol,
                            (char*)lsA + (it * 256 + tid) * 16);
#pragma unroll
            for (int it = 0; it < 4; ++it)
                gload_lds16(Wbf + (size_t)(c0 + it * 32 + grow) * DDIM + k0 + gcol,
                            (char*)lsW + (it * 256 + tid) * 16);
            __syncthreads();   // vmcnt drain -> tiles ready

#pragma unroll
            for (int ks = 0; ks < 2; ++ks) {
                short8 af[4], bg[4];
#pragma unroll
                for (int i = 0; i < 4; ++i) {
                    int r = wr * 64 + i * 16 + fr;
                    af[i] = *(const short8*)((const char*)lsA
                            + r * 128 + (((ks * 4 + q) ^ (r & 7)) << 4));
                }
#pragma unroll
                for (int j = 0; j < 4; ++j) {
                    int rc = wc * 64 + j * 16 + fr;
                    bg[j] = *(const short8*)((const char*)lsW
                            + rc * 128 + (((ks * 4 + q) ^ (rc & 7)) << 4));
                }
#pragma unroll
                for (int i = 0; i < 4; ++i)
#pragma unroll
                    for (int j = 0; j < 4; ++j)
                        acc[i][j] = __builtin_amdgcn_mfma_f32_16x16x32_bf16(
                            af[i], bg[j], acc[i][j], 0, 0, 0);
            }
        }

        // ---- epilogue (LDS-free): acc = 92.33*cos; exp2-sum; target ----
        int cj[4];
#pragma unroll
        for (int j = 0; j < 4; ++j) cj[j] = c0 + wc * 64 + j * 16 + fr;
#pragma unroll
        for (int i = 0; i < 4; ++i) {
#pragma unroll
            for (int v = 0; v < 4; ++v) {
                const int rl  = wr * 64 + i * 16 + q * 4 + v;
                const int lab = labels[m0 + rl];   // L1-hot
                float sm = 0.0f;
#pragma unroll
                for (int j = 0; j < 4; ++j) {
                    float a = acc[i][j][v];
                    sm += (cj[j] < CCLS) ? exp2f(a) : 0.0f;
                    if (cj[j] == lab) tcos[m0 + rl] = a * INV_XSCALE;
                }
                sm += __shfl_xor(sm, 1);
                sm += __shfl_xor(sm, 2);
                sm += __shfl_xor(sm, 4);
                sm += __shfl_xor(sm, 8);
                if (fr == 0) atomicAdd(&rowsum[m0 + rl], sm);
            }
        }
        // no barrier needed: next pair's k-loop starts with __syncthreads()
    }
}

// ---------------- kernel 4: final loss ----------------
__global__ __launch_bounds__(256) void arc_final(const float* __restrict__ rowsum,
                                                 const float* __restrict__ tcos,
                                                 float* __restrict__ out) {
    const int tid = threadIdx.x;
    const float cosM = 0.87758256189037271612f;  // cos(0.5)
    const float sinM = 0.47942553860420300027f;  // sin(0.5)
    float L = 0.0f;
    for (int n = tid; n < NROWS; n += 256) {
        float tc  = tcos[n];
        float tcl = fminf(fmaxf(tc, -1.0f + 1e-7f), 1.0f - 1e-7f);
        float num = 64.0f * (tcl * cosM - sinM * sqrtf(fmaxf(0.0f, 1.0f - tcl * tcl)));
        float den = __expf(num) + rowsum[n] - __expf(64.0f * tc);
        L += num - logf(den);
    }
    __shared__ float red[256];
    red[tid] = L;
    __syncthreads();
    for (int s = 128; s > 0; s >>= 1) {
        if (tid < s) red[tid] += red[tid + s];
        __syncthreads();
    }
    if (tid == 0) out[0] = -(red[0] / (float)NROWS);
}

// ---------------- launch ----------------
extern "C" void kernel_launch(void* const* d_in, const int* in_sizes, int n_in,
                              void* d_out, int out_size, void* d_ws, size_t ws_size,
                              hipStream_t stream) {
    const float* x      = (const float*)d_in[0];
    const float* W      = (const float*)d_in[1];
    const int*   labels = (const int*)d_in[2];
    float* out = (float*)d_out;
    char*  ws  = (char*)d_ws;

    const size_t WBF_BYTES = (size_t)CPAD * DDIM * 2;   // 102,498,304
    unsigned short* xn  = (unsigned short*)(ws);                     // 1 MB
    unsigned short* Wbf = (unsigned short*)(ws + 1048576);
    const size_t tail   = 1048576 + WBF_BYTES;

    float* rowsum = (float*)(ws + tail);
    float* tcos   = (float*)(ws + tail + 4096);

    (void)hipMemsetAsync(rowsum, 0, NROWS * sizeof(float), stream);

    norm_x<<<NROWS, 256, 0, stream>>>(x, xn);
    norm_w_cvt<<<CPAD / 4, 256, 0, stream>>>(W, Wbf);

    arc_gemm<<<GRID_BLOCKS, 256, 0, stream>>>(xn, Wbf, labels, rowsum, tcos);

    arc_final<<<1, 256, 0, stream>>>(rowsum, tcos, out);
}

// Round 19
// 184.864 us; speedup vs baseline: 1.5500x; 1.5500x over previous
//
#include <hip/hip_runtime.h>
#include <hip/hip_bf16.h>

using short8 = __attribute__((ext_vector_type(8))) short;
using f32x4  = __attribute__((ext_vector_type(4))) float;
using u32x4  = __attribute__((ext_vector_type(4))) unsigned int;

#define DDIM 512
#define NROWS 1024
#define CCLS 100000
#define NCT 782            // c-tiles of 128
#define CPAD (NCT * 128)   // 100096 padded classes
#define GRID_BLOCKS 1024   // 4/CU resident (33.8KB LDS, 128-reg bucket), persistent

#define XSCALE 92.33248261689366f      // 64 * log2(e): acc = XSCALE * cos
#define INV_XSCALE 0.010830424696358f  // ln2/64: cos = acc * INV_XSCALE

__device__ inline unsigned int f2bf(float f) {
    unsigned int u = __float_as_uint(f);
    u += 0x7FFFu + ((u >> 16) & 1u);
    return u >> 16;
}

__device__ inline unsigned int pk2(float x, float y) {
    unsigned int r;
    asm("v_cvt_pk_bf16_f32 %0, %1, %2" : "=v"(r) : "v"(x), "v"(y));
    return r;
}

__device__ inline void gload_lds16(const void* g, void* l) {
    __builtin_amdgcn_global_load_lds(
        (const __attribute__((address_space(1))) void*)g,
        (__attribute__((address_space(3))) void*)l, 16, 0, 0);
}

// ------- kernel 1: normalize x rows -> bf16, scaled by 64*log2(e) ----------
__global__ __launch_bounds__(256) void norm_x(const float* __restrict__ x,
                                              unsigned short* __restrict__ xn) {
    const int row = blockIdx.x;
    const int tid = threadIdx.x;
    float2 v = *(const float2*)(x + (size_t)row * DDIM + tid * 2);
    float ss = v.x * v.x + v.y * v.y;
#pragma unroll
    for (int m = 1; m < 64; m <<= 1) ss += __shfl_xor(ss, m);
    __shared__ float wsum[4];
    if ((tid & 63) == 0) wsum[tid >> 6] = ss;
    __syncthreads();
    float inv = XSCALE / sqrtf(wsum[0] + wsum[1] + wsum[2] + wsum[3]);
    unsigned int packed = f2bf(v.x * inv) | (f2bf(v.y * inv) << 16);
    ((unsigned int*)xn)[(size_t)row * (DDIM / 2) + tid] = packed;
}

// ------- kernel 2: W -> PRE-NORMALIZED bf16 (one wave per row) --------------
__global__ __launch_bounds__(256) void norm_w_cvt(const float* __restrict__ W,
                                                  unsigned short* __restrict__ Wbf) {
    const int row  = blockIdx.x * 4 + (threadIdx.x >> 6);
    const int lane = threadIdx.x & 63;
    if (row < CCLS) {
        const float4* p = (const float4*)(W + (size_t)row * DDIM + lane * 8);
        float4 a = p[0], b = p[1];
        float ss = a.x*a.x + a.y*a.y + a.z*a.z + a.w*a.w
                 + b.x*b.x + b.y*b.y + b.z*b.z + b.w*b.w;
#pragma unroll
        for (int m = 1; m < 64; m <<= 1) ss += __shfl_xor(ss, m);
        float inv = (ss > 0.0f) ? (1.0f / sqrtf(ss)) : 0.0f;
        u32x4 u = { pk2(a.x * inv, a.y * inv), pk2(a.z * inv, a.w * inv),
                    pk2(b.x * inv, b.y * inv), pk2(b.z * inv, b.w * inv) };
        *(u32x4*)(Wbf + (size_t)row * DDIM + lane * 8) = u;
    } else {
        *(u32x4*)(Wbf + (size_t)row * DDIM + lane * 8) = u32x4{0u, 0u, 0u, 0u};
    }
}

// ---------------- kernel 3: GEMM + exp-rowsum + target (R10 champion) -------
// 128x128 tile, BK=64, 4 waves (2x2), acc[4][4], 16x16x32 MFMA, single
// 32KB LDS buffer, 2 barriers/k-step, pure-DMA staging (pre-swizzled
// sources, rule #21), persistent XCD-windowed pairs.
// Epilogue: LDS-staged lrow reduction + COALESCED tid<128 atomics (R18
// lesson: scattered per-lane atomics cost 27MB of HBM write + serialization).
// Numeric trims (proven absmax 0.0): prenorm Wbf + XSCALE in xn -> epilogue
// is one exp2f per element, no winv.
__global__ __launch_bounds__(256, 4) void arc_gemm(
    const unsigned short* __restrict__ xn,   // [1024][512] bf16 (x 92.33/||x||)
    const unsigned short* __restrict__ Wbf,  // [CPAD][512] bf16 (W/||W||, 0-pad)
    const int* __restrict__ labels,          // [1024]
    float* __restrict__ rowsum,              // [1024] (pre-zeroed)
    float* __restrict__ tcos)                // [1024]
{
    __shared__ __align__(16) unsigned short lsA[128 * 64]; // 16 KB
    __shared__ __align__(16) unsigned short lsW[128 * 64]; // 16 KB
    __shared__ float lrow[128];
    __shared__ int   llab[128];

    const int tid  = threadIdx.x;
    const int lane = tid & 63;
    const int wid  = tid >> 6;
    const int wr   = wid >> 1, wc = wid & 1;
    const int q    = lane >> 4;
    const int fr   = lane & 15;

    // DMA geometry: dest linear, source column pre-swizzled by row&7
    // -> conflict-free 16-row ds_read_b128 fragments (R1/R10 proven).
    const int grow = tid >> 3;
    const int gcol = ((tid & 7) ^ (grow & 7)) * 8;   // bf16 units

    const int x    = blockIdx.x & 7;
    const int sidx = blockIdx.x >> 3;
    const int nct  = (NCT - 1 - x) / 8 + 1;
    const int npairs = nct * 8;

    for (int p = sidx; p < npairs; p += GRID_BLOCKS / 8) {
        const int c0 = (x + 8 * (p >> 3)) * 128;
        const int m0 = (p & 7) * 128;

        if (tid < 128) { lrow[tid] = 0.0f; llab[tid] = labels[m0 + tid]; }

        f32x4 acc[4][4];
#pragma unroll
        for (int i = 0; i < 4; ++i)
#pragma unroll
            for (int j = 0; j < 4; ++j) acc[i][j] = (f32x4)(0.0f);

#pragma unroll 1
        for (int k = 0; k < 8; ++k) {
            const int k0 = k * 64;
            __syncthreads();   // prev compute done reading LDS; publishes lrow/llab
#pragma unroll
            for (int it = 0; it < 4; ++it)
                gload_lds16(xn + (size_t)(m0 + it * 32 + grow) * DDIM + k0 + gcol,
                            (char*)lsA + (it * 256 + tid) * 16);
#pragma unroll
            for (int it = 0; it < 4; ++it)
                gload_lds16(Wbf + (size_t)(c0 + it * 32 + grow) * DDIM + k0 + gcol,
                            (char*)lsW + (it * 256 + tid) * 16);
            __syncthreads();   // vmcnt drain -> tiles ready

#pragma unroll
            for (int ks = 0; ks < 2; ++ks) {
                short8 af[4], bg[4];
#pragma unroll
                for (int i = 0; i < 4; ++i) {
                    int r = wr * 64 + i * 16 + fr;
                    af[i] = *(const short8*)((const char*)lsA
                            + r * 128 + (((ks * 4 + q) ^ (r & 7)) << 4));
                }
#pragma unroll
                for (int j = 0; j < 4; ++j) {
                    int rc = wc * 64 + j * 16 + fr;
                    bg[j] = *(const short8*)((const char*)lsW
                            + rc * 128 + (((ks * 4 + q) ^ (rc & 7)) << 4));
                }
#pragma unroll
                for (int i = 0; i < 4; ++i)
#pragma unroll
                    for (int j = 0; j < 4; ++j)
                        acc[i][j] = __builtin_amdgcn_mfma_f32_16x16x32_bf16(
                            af[i], bg[j], acc[i][j], 0, 0, 0);
            }
        }

        // ---- epilogue: acc = 92.33*cos; exp2-sum -> lrow; target capture ----
        int cj[4];
#pragma unroll
        for (int j = 0; j < 4; ++j) cj[j] = c0 + wc * 64 + j * 16 + fr;
#pragma unroll
        for (int i = 0; i < 4; ++i) {
#pragma unroll
            for (int v = 0; v < 4; ++v) {
                const int rl  = wr * 64 + i * 16 + q * 4 + v;
                const int lab = llab[rl];
                float sm = 0.0f;
#pragma unroll
                for (int j = 0; j < 4; ++j) {
                    float a = acc[i][j][v];
                    sm += (cj[j] < CCLS) ? exp2f(a) : 0.0f;
                    if (cj[j] == lab) tcos[m0 + rl] = a * INV_XSCALE;
                }
                sm += __shfl_xor(sm, 1);
                sm += __shfl_xor(sm, 2);
                sm += __shfl_xor(sm, 4);
                sm += __shfl_xor(sm, 8);
                if (fr == 0) atomicAdd(&lrow[rl], sm);
            }
        }
        __syncthreads();
        if (tid < 128) atomicAdd(&rowsum[m0 + tid], lrow[tid]);   // coalesced
        // next pair: same-tid lrow/llab rewrite; k-loop barrier publishes
    }
}

// ---------------- kernel 4: final loss ----------------
__global__ __launch_bounds__(256) void arc_final(const float* __restrict__ rowsum,
                                                 const float* __restrict__ tcos,
                                                 float* __restrict__ out) {
    const int tid = threadIdx.x;
    const float cosM = 0.87758256189037271612f;  // cos(0.5)
    const float sinM = 0.47942553860420300027f;  // sin(0.5)
    float L = 0.0f;
    for (int n = tid; n < NROWS; n += 256) {
        float tc  = tcos[n];
        float tcl = fminf(fmaxf(tc, -1.0f + 1e-7f), 1.0f - 1e-7f);
        float num = 64.0f * (tcl * cosM - sinM * sqrtf(fmaxf(0.0f, 1.0f - tcl * tcl)));
        float den = __expf(num) + rowsum[n] - __expf(64.0f * tc);
        L += num - logf(den);
    }
    __shared__ float red[256];
    red[tid] = L;
    __syncthreads();
    for (int s = 128; s > 0; s >>= 1) {
        if (tid < s) red[tid] += red[tid + s];
        __syncthreads();
    }
    if (tid == 0) out[0] = -(red[0] / (float)NROWS);
}

// ---------------- launch ----------------
extern "C" void kernel_launch(void* const* d_in, const int* in_sizes, int n_in,
                              void* d_out, int out_size, void* d_ws, size_t ws_size,
                              hipStream_t stream) {
    const float* x      = (const float*)d_in[0];
    const float* W      = (const float*)d_in[1];
    const int*   labels = (const int*)d_in[2];
    float* out = (float*)d_out;
    char*  ws  = (char*)d_ws;

    const size_t WBF_BYTES = (size_t)CPAD * DDIM * 2;   // 102,498,304
    unsigned short* xn  = (unsigned short*)(ws);                     // 1 MB
    unsigned short* Wbf = (unsigned short*)(ws + 1048576);
    const size_t tail   = 1048576 + WBF_BYTES;

    float* rowsum = (float*)(ws + tail);
    float* tcos   = (float*)(ws + tail + 4096);

    (void)hipMemsetAsync(rowsum, 0, NROWS * sizeof(float), stream);

    norm_x<<<NROWS, 256, 0, stream>>>(x, xn);
    norm_w_cvt<<<CPAD / 4, 256, 0, stream>>>(W, Wbf);

    arc_gemm<<<GRID_BLOCKS, 256, 0, stream>>>(xn, Wbf, labels, rowsum, tcos);

    arc_final<<<1, 256, 0, stream>>>(rowsum, tcos, out);
}

// Round 20
// 149.692 us; speedup vs baseline: 1.9142x; 1.2350x over previous
//
#include <hip/hip_runtime.h>
#include <hip/hip_bf16.h>

using f32x4 = __attribute__((ext_vector_type(4))) float;

#define DDIM 512
#define NROWS 1024
#define CCLS 100000
#define NCT 782            // c-tiles of 128
#define CPAD (NCT * 128)   // 100096 padded classes (96 zero rows -> exp2(0)=1 each)
#define NPADC ((float)(CPAD - CCLS))   // 96.0
#define GRID_BLOCKS 1024   // 4/CU resident, persistent XCD-windowed

#define XSCALE 92.33248261689366f      // 64 * log2(e): acc = XSCALE * cos (log2 units)

__device__ inline void gload_lds16(const void* g, void* l) {
    __builtin_amdgcn_global_load_lds(
        (const __attribute__((address_space(1))) void*)g,
        (__attribute__((address_space(3))) void*)l, 16, 0, 0);
}

// pack 4 floats -> 4 fp8 e4m3 in one u32
__device__ inline unsigned int pk4_fp8(float a, float b, float c, float d) {
    int w = __builtin_amdgcn_cvt_pk_fp8_f32(a, b, 0, false);
    w = __builtin_amdgcn_cvt_pk_fp8_f32(c, d, w, true);
    return (unsigned int)w;
}

// ------- kernel 1: normalize x rows -> fp8, scaled by 64*log2(e) -----------
__global__ __launch_bounds__(256) void norm_x(const float* __restrict__ x,
                                              unsigned char* __restrict__ xf8) {
    const int row = blockIdx.x;
    const int tid = threadIdx.x;
    float2 v = *(const float2*)(x + (size_t)row * DDIM + tid * 2);
    float ss = v.x * v.x + v.y * v.y;
#pragma unroll
    for (int m = 1; m < 64; m <<= 1) ss += __shfl_xor(ss, m);
    __shared__ float wsum[4];
    if ((tid & 63) == 0) wsum[tid >> 6] = ss;
    __syncthreads();
    float inv = XSCALE / sqrtf(wsum[0] + wsum[1] + wsum[2] + wsum[3]);
    if (tid < 128) {
        float4 a = *(const float4*)(x + (size_t)row * DDIM + tid * 4);  // L1-hot
        ((unsigned int*)xf8)[(size_t)row * (DDIM / 4) + tid] =
            pk4_fp8(a.x * inv, a.y * inv, a.z * inv, a.w * inv);
    }
}

// ------- kernel 2: W -> PRE-NORMALIZED fp8 (one wave per row) --------------
__global__ __launch_bounds__(256) void norm_w_cvt(const float* __restrict__ W,
                                                  unsigned char* __restrict__ Wf8) {
    const int row  = blockIdx.x * 4 + (threadIdx.x >> 6);
    const int lane = threadIdx.x & 63;
    if (row < CCLS) {
        const float4* p = (const float4*)(W + (size_t)row * DDIM + lane * 8);
        float4 a = p[0], b = p[1];
        float ss = a.x*a.x + a.y*a.y + a.z*a.z + a.w*a.w
                 + b.x*b.x + b.y*b.y + b.z*b.z + b.w*b.w;
#pragma unroll
        for (int m = 1; m < 64; m <<= 1) ss += __shfl_xor(ss, m);
        float inv = (ss > 0.0f) ? (1.0f / sqrtf(ss)) : 0.0f;
        uint2 u = { pk4_fp8(a.x * inv, a.y * inv, a.z * inv, a.w * inv),
                    pk4_fp8(b.x * inv, b.y * inv, b.z * inv, b.w * inv) };
        *(uint2*)(Wf8 + (size_t)row * DDIM + lane * 8) = u;
    } else {
        *(uint2*)(Wf8 + (size_t)row * DDIM + lane * 8) = make_uint2(0u, 0u);
    }
}

// ------- kernel 3: EXACT target cosine (fp32 gather-dot, 1 wave/sample) ----
__global__ __launch_bounds__(256) void target_dot(const float* __restrict__ x,
                                                  const float* __restrict__ W,
                                                  const int* __restrict__ labels,
                                                  float* __restrict__ tcos) {
    const int n    = blockIdx.x * 4 + (threadIdx.x >> 6);
    const int lane = threadIdx.x & 63;
    const int lab  = labels[n];
    const float4* px = (const float4*)(x + (size_t)n * DDIM + lane * 8);
    const float4* pw = (const float4*)(W + (size_t)lab * DDIM + lane * 8);
    float4 a0 = px[0], a1 = px[1], b0 = pw[0], b1 = pw[1];
    float xw = a0.x*b0.x + a0.y*b0.y + a0.z*b0.z + a0.w*b0.w
             + a1.x*b1.x + a1.y*b1.y + a1.z*b1.z + a1.w*b1.w;
    float xx = a0.x*a0.x + a0.y*a0.y + a0.z*a0.z + a0.w*a0.w
             + a1.x*a1.x + a1.y*a1.y + a1.z*a1.z + a1.w*a1.w;
    float ww = b0.x*b0.x + b0.y*b0.y + b0.z*b0.z + b0.w*b0.w
             + b1.x*b1.x + b1.y*b1.y + b1.z*b1.z + b1.w*b1.w;
#pragma unroll
    for (int m = 1; m < 64; m <<= 1) {
        xw += __shfl_xor(xw, m);
        xx += __shfl_xor(xx, m);
        ww += __shfl_xor(ww, m);
    }
    if (lane == 0) tcos[n] = xw / sqrtf(xx * ww);
}

// ---------------- kernel 4: fp8 GEMM + exp2-rowsum --------------------------
// Champion structure (128x128 tile, 4 waves 2x2, acc[4][4], single buffer,
// 2 barriers/k-step, pure-DMA staging w/ rule-#21 pre-swizzle, persistent
// XCD-windowed pairs) with fp8 e4m3 operands:
//  - BK=128 keeps rows at 128B (8x16B slots) -> identical DMA geometry and
//    XOR swizzle; fragment reads are b64 (512B/wave = 4 bank-cycle floor)
//  - per pair: LDS traffic 768->384 KB, DMA bytes halve, 4 k-steps (not 8)
//  - epilogue: unconditional exp2 sum (padded classes add exactly 96,
//    subtracted in arc_final); no label logic (target_dot is exact)
__global__ __launch_bounds__(256, 4) void arc_gemm(
    const unsigned char* __restrict__ xf8,   // [1024][512] fp8 (x 92.33/||x||)
    const unsigned char* __restrict__ Wf8,   // [CPAD][512] fp8 (W/||W||, 0-pad)
    float* __restrict__ rowsum)              // [1024] (pre-zeroed)
{
    __shared__ __align__(16) char lsA[128 * 128]; // 16 KB (128 rows x 128B)
    __shared__ __align__(16) char lsW[128 * 128]; // 16 KB
    __shared__ float lrow[128];

    const int tid  = threadIdx.x;
    const int lane = tid & 63;
    const int wid  = tid >> 6;
    const int wr   = wid >> 1, wc = wid & 1;
    const int q    = lane >> 4;
    const int fr   = lane & 15;

    // DMA: dest linear, source 16B-slot pre-swizzled by row&7 (rule #21)
    const int grow = tid >> 3;
    const int gcol = ((tid & 7) ^ (grow & 7)) * 16;   // byte col in 128B chunk

    const int x    = blockIdx.x & 7;
    const int sidx = blockIdx.x >> 3;
    const int nct  = (NCT - 1 - x) / 8 + 1;
    const int npairs = nct * 8;

    for (int p = sidx; p < npairs; p += GRID_BLOCKS / 8) {
        const int c0 = (x + 8 * (p >> 3)) * 128;
        const int m0 = (p & 7) * 128;

        if (tid < 128) lrow[tid] = 0.0f;

        f32x4 acc[4][4];
#pragma unroll
        for (int i = 0; i < 4; ++i)
#pragma unroll
            for (int j = 0; j < 4; ++j) acc[i][j] = (f32x4)(0.0f);

#pragma unroll 1
        for (int k = 0; k < 4; ++k) {          // BK=128 fp8 = 128 bytes
            const int k0 = k * 128;
            __syncthreads();   // prev compute done reading LDS; publishes lrow
#pragma unroll
            for (int it = 0; it < 4; ++it)
                gload_lds16(xf8 + (size_t)(m0 + it * 32 + grow) * DDIM + k0 + gcol,
                            lsA + (it * 256 + tid) * 16);
#pragma unroll
            for (int it = 0; it < 4; ++it)
                gload_lds16(Wf8 + (size_t)(c0 + it * 32 + grow) * DDIM + k0 + gcol,
                            lsW + (it * 256 + tid) * 16);
            __syncthreads();   // vmcnt drain -> tiles ready

#pragma unroll
            for (int ks = 0; ks < 4; ++ks) {   // 4 x K=32 within the 128B row
                const int kb = ks * 32 + q * 8;
                long af[4], bg[4];
#pragma unroll
                for (int i = 0; i < 4; ++i) {
                    int r = wr * 64 + i * 16 + fr;
                    af[i] = *(const long*)(lsA + r * 128 + (kb ^ ((r & 7) << 4)));
                }
#pragma unroll
                for (int j = 0; j < 4; ++j) {
                    int rc = wc * 64 + j * 16 + fr;
                    bg[j] = *(const long*)(lsW + rc * 128 + (kb ^ ((rc & 7) << 4)));
                }
#pragma unroll
                for (int i = 0; i < 4; ++i)
#pragma unroll
                    for (int j = 0; j < 4; ++j)
                        acc[i][j] = __builtin_amdgcn_mfma_f32_16x16x32_fp8_fp8(
                            af[i], bg[j], acc[i][j], 0, 0, 0);
            }
        }

        // ---- epilogue: acc = 92.33*cos (log2 units); exp2-sum -> lrow ----
#pragma unroll
        for (int i = 0; i < 4; ++i) {
#pragma unroll
            for (int v = 0; v < 4; ++v) {
                const int rl = wr * 64 + i * 16 + q * 4 + v;
                float sm = exp2f(acc[i][0][v]) + exp2f(acc[i][1][v])
                         + exp2f(acc[i][2][v]) + exp2f(acc[i][3][v]);
                sm += __shfl_xor(sm, 1);
                sm += __shfl_xor(sm, 2);
                sm += __shfl_xor(sm, 4);
                sm += __shfl_xor(sm, 8);
                if (fr == 0) atomicAdd(&lrow[rl], sm);
            }
        }
        __syncthreads();
        if (tid < 128) atomicAdd(&rowsum[m0 + tid], lrow[tid]);   // coalesced
    }
}

// ---------------- kernel 5: final loss ----------------
__global__ __launch_bounds__(256) void arc_final(const float* __restrict__ rowsum,
                                                 const float* __restrict__ tcos,
                                                 float* __restrict__ out) {
    const int tid = threadIdx.x;
    const float cosM = 0.87758256189037271612f;  // cos(0.5)
    const float sinM = 0.47942553860420300027f;  // sin(0.5)
    float L = 0.0f;
    for (int n = tid; n < NROWS; n += 256) {
        float tc  = tcos[n];
        float tcl = fminf(fmaxf(tc, -1.0f + 1e-7f), 1.0f - 1e-7f);
        float num = 64.0f * (tcl * cosM - sinM * sqrtf(fmaxf(0.0f, 1.0f - tcl * tcl)));
        // rowsum includes all CPAD classes (incl. target, incl. 96 pad ones)
        float den = __expf(num) + (rowsum[n] - NPADC) - __expf(64.0f * tc);
        L += num - logf(den);
    }
    __shared__ float red[256];
    red[tid] = L;
    __syncthreads();
    for (int s = 128; s > 0; s >>= 1) {
        if (tid < s) red[tid] += red[tid + s];
        __syncthreads();
    }
    if (tid == 0) out[0] = -(red[0] / (float)NROWS);
}

// ---------------- launch ----------------
extern "C" void kernel_launch(void* const* d_in, const int* in_sizes, int n_in,
                              void* d_out, int out_size, void* d_ws, size_t ws_size,
                              hipStream_t stream) {
    const float* x      = (const float*)d_in[0];
    const float* W      = (const float*)d_in[1];
    const int*   labels = (const int*)d_in[2];
    float* out = (float*)d_out;
    char*  ws  = (char*)d_ws;

    const size_t XF8_BYTES = (size_t)NROWS * DDIM;   // 524,288
    const size_t WF8_BYTES = (size_t)CPAD * DDIM;    // 51,249,152
    unsigned char* xf8 = (unsigned char*)(ws);
    unsigned char* Wf8 = (unsigned char*)(ws + XF8_BYTES);
    float* rowsum      = (float*)(ws + XF8_BYTES + WF8_BYTES);
    float* tcos        = (float*)(ws + XF8_BYTES + WF8_BYTES + 4096);

    (void)hipMemsetAsync(rowsum, 0, NROWS * sizeof(float), stream);

    norm_x<<<NROWS, 256, 0, stream>>>(x, xf8);
    norm_w_cvt<<<CPAD / 4, 256, 0, stream>>>(W, Wf8);
    target_dot<<<NROWS / 4, 256, 0, stream>>>(x, W, labels, tcos);

    arc_gemm<<<GRID_BLOCKS, 256, 0, stream>>>(xf8, Wf8, rowsum);

    arc_final<<<1, 256, 0, stream>>>(rowsum, tcos, out);
}

// Round 21
// 139.810 us; speedup vs baseline: 2.0495x; 1.0707x over previous
//
#include <hip/hip_runtime.h>
#include <hip/hip_bf16.h>

using f32x4 = __attribute__((ext_vector_type(4))) float;
using i32x8 = __attribute__((ext_vector_type(8))) int;
using u32x4 = __attribute__((ext_vector_type(4))) unsigned int;

#define DDIM 512
#define NROWS 1024
#define CCLS 100000
#define NCT 782            // c-tiles of 128
#define CPAD (NCT * 128)   // 100096 padded classes (96 zero rows -> exp2(0)=1)
#define NPADC ((float)(CPAD - CCLS))   // 96.0
#define GRID_BLOCKS 1024   // 4/CU resident, persistent XCD-windowed

#define XSCALE 92.33248261689366f      // 64 * log2(e): acc = XSCALE * cos (log2 units)
#define SCL1 0x7F7F7F7F                // E8M0 scale = 1.0 in every byte

__device__ inline void gload_lds16(const void* g, void* l) {
    __builtin_amdgcn_global_load_lds(
        (const __attribute__((address_space(1))) void*)g,
        (__attribute__((address_space(3))) void*)l, 16, 0, 0);
}

// pack 4 floats -> 4 fp8 e4m3 in one u32
__device__ inline unsigned int pk4_fp8(float a, float b, float c, float d) {
    int w = __builtin_amdgcn_cvt_pk_fp8_f32(a, b, 0, false);
    w = __builtin_amdgcn_cvt_pk_fp8_f32(c, d, w, true);
    return (unsigned int)w;
}

// read one K=128 fp8 fragment (32B/lane) from a swizzled 128B LDS row
__device__ inline i32x8 read_frag128(const char* base, int row, int q) {
    const int sw = row & 7;
    u32x4 lo = *(const u32x4*)(base + row * 128 + (((2 * q)     ^ sw) << 4));
    u32x4 hi = *(const u32x4*)(base + row * 128 + (((2 * q + 1) ^ sw) << 4));
    i32x8 r = { (int)lo.x, (int)lo.y, (int)lo.z, (int)lo.w,
                (int)hi.x, (int)hi.y, (int)hi.z, (int)hi.w };
    return r;
}

// ------- kernel 1: x-norm -> fp8 (scaled 64*log2e) + EXACT target cosine ---
// one wave per sample: reads x row once, W[label] row once.
__global__ __launch_bounds__(256) void prep_x(const float* __restrict__ x,
                                              const float* __restrict__ W,
                                              const int* __restrict__ labels,
                                              unsigned char* __restrict__ xf8,
                                              float* __restrict__ tcos) {
    const int n    = blockIdx.x * 4 + (threadIdx.x >> 6);
    const int lane = threadIdx.x & 63;
    const int lab  = labels[n];
    const float4* px = (const float4*)(x + (size_t)n * DDIM + lane * 8);
    const float4* pw = (const float4*)(W + (size_t)lab * DDIM + lane * 8);
    float4 a0 = px[0], a1 = px[1], b0 = pw[0], b1 = pw[1];
    float xw = a0.x*b0.x + a0.y*b0.y + a0.z*b0.z + a0.w*b0.w
             + a1.x*b1.x + a1.y*b1.y + a1.z*b1.z + a1.w*b1.w;
    float xx = a0.x*a0.x + a0.y*a0.y + a0.z*a0.z + a0.w*a0.w
             + a1.x*a1.x + a1.y*a1.y + a1.z*a1.z + a1.w*a1.w;
    float ww = b0.x*b0.x + b0.y*b0.y + b0.z*b0.z + b0.w*b0.w
             + b1.x*b1.x + b1.y*b1.y + b1.z*b1.z + b1.w*b1.w;
#pragma unroll
    for (int m = 1; m < 64; m <<= 1) {
        xw += __shfl_xor(xw, m);
        xx += __shfl_xor(xx, m);
        ww += __shfl_xor(ww, m);
    }
    float inv = XSCALE * __frsqrt_rn(xx);
    uint2 u = { pk4_fp8(a0.x * inv, a0.y * inv, a0.z * inv, a0.w * inv),
                pk4_fp8(a1.x * inv, a1.y * inv, a1.z * inv, a1.w * inv) };
    *(uint2*)(xf8 + (size_t)n * DDIM + lane * 8) = u;
    if (lane == 0) tcos[n] = xw / sqrtf(xx * ww);
}

// ------- kernel 2: W -> PRE-NORMALIZED fp8 (one wave per row) --------------
__global__ __launch_bounds__(256) void norm_w_cvt(const float* __restrict__ W,
                                                  unsigned char* __restrict__ Wf8) {
    const int row  = blockIdx.x * 4 + (threadIdx.x >> 6);
    const int lane = threadIdx.x & 63;
    if (row < CCLS) {
        const float4* p = (const float4*)(W + (size_t)row * DDIM + lane * 8);
        float4 a = p[0], b = p[1];
        float ss = a.x*a.x + a.y*a.y + a.z*a.z + a.w*a.w
                 + b.x*b.x + b.y*b.y + b.z*b.z + b.w*b.w;
#pragma unroll
        for (int m = 1; m < 64; m <<= 1) ss += __shfl_xor(ss, m);
        float inv = (ss > 0.0f) ? (1.0f / sqrtf(ss)) : 0.0f;
        uint2 u = { pk4_fp8(a.x * inv, a.y * inv, a.z * inv, a.w * inv),
                    pk4_fp8(b.x * inv, b.y * inv, b.z * inv, b.w * inv) };
        *(uint2*)(Wf8 + (size_t)row * DDIM + lane * 8) = u;
    } else {
        *(uint2*)(Wf8 + (size_t)row * DDIM + lane * 8) = make_uint2(0u, 0u);
    }
}

// ---------------- kernel 3: MX-fp8 GEMM + exp2-rowsum -----------------------
// Champion structure (128x128 tile, 4 waves 2x2, single 32KB buffer,
// 2 barriers/k-chunk, pure-DMA staging w/ rule-#21 pre-swizzle, persistent
// XCD-windowed pairs) upgraded to mfma_scale_f32_16x16x128_f8f6f4:
//  - one MFMA consumes a FULL 128B LDS row slice (K=128) at ~2x fp8 rate
//  - frag = 2 x ds_read_b128 (same swizzle involution, conflict-free)
//  - scales fixed at E8M0 1.0 (0x7F); fmt args 0 = fp8 e4m3
//  - register discipline: bg[4] held (32 VGPR), af reloaded per-i (8 VGPR),
//    acc 64 AGPR -> ~122 unified regs, stays in the 16-wave/CU bucket
__global__ __launch_bounds__(256, 4) void arc_gemm(
    const unsigned char* __restrict__ xf8,   // [1024][512] fp8 (x 92.33/||x||)
    const unsigned char* __restrict__ Wf8,   // [CPAD][512] fp8 (W/||W||, 0-pad)
    float* __restrict__ rowsum)              // [1024] (pre-zeroed)
{
    __shared__ __align__(16) char lsA[128 * 128]; // 16 KB (128 rows x 128B)
    __shared__ __align__(16) char lsW[128 * 128]; // 16 KB
    __shared__ float lrow[128];

    const int tid  = threadIdx.x;
    const int lane = tid & 63;
    const int wid  = tid >> 6;
    const int wr   = wid >> 1, wc = wid & 1;
    const int q    = lane >> 4;
    const int fr   = lane & 15;

    // DMA: dest linear, source 16B-slot pre-swizzled by row&7 (rule #21)
    const int grow = tid >> 3;
    const int gcol = ((tid & 7) ^ (grow & 7)) * 16;   // byte col in 128B chunk

    const int x    = blockIdx.x & 7;
    const int sidx = blockIdx.x >> 3;
    const int nct  = (NCT - 1 - x) / 8 + 1;
    const int npairs = nct * 8;

    for (int p = sidx; p < npairs; p += GRID_BLOCKS / 8) {
        const int c0 = (x + 8 * (p >> 3)) * 128;
        const int m0 = (p & 7) * 128;

        if (tid < 128) lrow[tid] = 0.0f;

        f32x4 acc[4][4];
#pragma unroll
        for (int i = 0; i < 4; ++i)
#pragma unroll
            for (int j = 0; j < 4; ++j) acc[i][j] = (f32x4)(0.0f);

#pragma unroll 1
        for (int k = 0; k < 4; ++k) {          // 4 chunks of K=128 (128B rows)
            const int k0 = k * 128;
            __syncthreads();   // prev compute done reading LDS; publishes lrow
#pragma unroll
            for (int it = 0; it < 4; ++it)
                gload_lds16(xf8 + (size_t)(m0 + it * 32 + grow) * DDIM + k0 + gcol,
                            lsA + (it * 256 + tid) * 16);
#pragma unroll
            for (int it = 0; it < 4; ++it)
                gload_lds16(Wf8 + (size_t)(c0 + it * 32 + grow) * DDIM + k0 + gcol,
                            lsW + (it * 256 + tid) * 16);
            __syncthreads();   // vmcnt drain -> tiles ready

            i32x8 bg[4];
#pragma unroll
            for (int j = 0; j < 4; ++j)
                bg[j] = read_frag128(lsW, wc * 64 + j * 16 + fr, q);
#pragma unroll
            for (int i = 0; i < 4; ++i) {
                i32x8 af = read_frag128(lsA, wr * 64 + i * 16 + fr, q);
#pragma unroll
                for (int j = 0; j < 4; ++j)
                    acc[i][j] = __builtin_amdgcn_mfma_scale_f32_16x16x128_f8f6f4(
                        af, bg[j], acc[i][j], 0, 0, 0, SCL1, 0, SCL1);
            }
        }

        // ---- epilogue: acc = 92.33*cos (log2 units); exp2-sum -> lrow ----
#pragma unroll
        for (int i = 0; i < 4; ++i) {
#pragma unroll
            for (int v = 0; v < 4; ++v) {
                const int rl = wr * 64 + i * 16 + q * 4 + v;
                float sm = exp2f(acc[i][0][v]) + exp2f(acc[i][1][v])
                         + exp2f(acc[i][2][v]) + exp2f(acc[i][3][v]);
                sm += __shfl_xor(sm, 1);
                sm += __shfl_xor(sm, 2);
                sm += __shfl_xor(sm, 4);
                sm += __shfl_xor(sm, 8);
                if (fr == 0) atomicAdd(&lrow[rl], sm);
            }
        }
        __syncthreads();
        if (tid < 128) atomicAdd(&rowsum[m0 + tid], lrow[tid]);   // coalesced
    }
}

// ---------------- kernel 4: final loss ----------------
__global__ __launch_bounds__(256) void arc_final(const float* __restrict__ rowsum,
                                                 const float* __restrict__ tcos,
                                                 float* __restrict__ out) {
    const int tid = threadIdx.x;
    const float cosM = 0.87758256189037271612f;  // cos(0.5)
    const float sinM = 0.47942553860420300027f;  // sin(0.5)
    float L = 0.0f;
    for (int n = tid; n < NROWS; n += 256) {
        float tc  = tcos[n];
        float tcl = fminf(fmaxf(tc, -1.0f + 1e-7f), 1.0f - 1e-7f);
        float num = 64.0f * (tcl * cosM - sinM * sqrtf(fmaxf(0.0f, 1.0f - tcl * tcl)));
        // rowsum includes all CPAD classes (incl. target, incl. 96 pad ones)
        float den = __expf(num) + (rowsum[n] - NPADC) - __expf(64.0f * tc);
        L += num - logf(den);
    }
    __shared__ float red[256];
    red[tid] = L;
    __syncthreads();
    for (int s = 128; s > 0; s >>= 1) {
        if (tid < s) red[tid] += red[tid + s];
        __syncthreads();
    }
    if (tid == 0) out[0] = -(red[0] / (float)NROWS);
}

// ---------------- launch ----------------
extern "C" void kernel_launch(void* const* d_in, const int* in_sizes, int n_in,
                              void* d_out, int out_size, void* d_ws, size_t ws_size,
                              hipStream_t stream) {
    const float* x      = (const float*)d_in[0];
    const float* W      = (const float*)d_in[1];
    const int*   labels = (const int*)d_in[2];
    float* out = (float*)d_out;
    char*  ws  = (char*)d_ws;

    const size_t XF8_BYTES = (size_t)NROWS * DDIM;   // 524,288
    const size_t WF8_BYTES = (size_t)CPAD * DDIM;    // 51,249,152
    unsigned char* xf8 = (unsigned char*)(ws);
    unsigned char* Wf8 = (unsigned char*)(ws + XF8_BYTES);
    float* rowsum      = (float*)(ws + XF8_BYTES + WF8_BYTES);
    float* tcos        = (float*)(ws + XF8_BYTES + WF8_BYTES + 4096);

    (void)hipMemsetAsync(rowsum, 0, NROWS * sizeof(float), stream);

    prep_x<<<NROWS / 4, 256, 0, stream>>>(x, W, labels, xf8, tcos);
    norm_w_cvt<<<CPAD / 4, 256, 0, stream>>>(W, Wf8);

    arc_gemm<<<GRID_BLOCKS, 256, 0, stream>>>(xf8, Wf8, rowsum);

    arc_final<<<1, 256, 0, stream>>>(rowsum, tcos, out);
}